// Round 1
// baseline (360.134 us; speedup 1.0000x reference)
//
#include <hip/hip_runtime.h>
#include <hip/hip_bf16.h>
#include <cstdint>

#define B_DIM 8192
#define N_DIM 64
#define C_DIM 16
#define D_DIM 1024
#define NUM 32
#define NCAUSAL 16
#define K_RANGES 8
#define HS 1024
#define HP 1024
#define TAU 0.7f
#define SMOOTH 0.1f

typedef __bf16 bf16x8 __attribute__((ext_vector_type(8)));
typedef float f32x16 __attribute__((ext_vector_type(16)));

typedef const __attribute__((address_space(1))) uint32_t* gas_ptr;
typedef __attribute__((address_space(3))) uint32_t* las_ptr;

__device__ __forceinline__ void gld_lds16(const void* g, void* l) {
    __builtin_amdgcn_global_load_lds((gas_ptr)(uintptr_t)g,
                                     (las_ptr)(uint32_t)(uintptr_t)l,
                                     16, 0, 0);
}

// ---------------------------------------------------------------------------
// 8-phase 256x256 GEMM (T2+T3+T4+T5 stack, plain HIP).
// 512 threads = 8 waves (2M x 4N), per-wave 128x64, MFMA 32x32x16.
// BK=64 (8 x 16B chunks/row), chunk swizzle c ^= (r&7) (stage pre-swizzles
// the GLOBAL source; LDS dest stays linear for global_load_lds).
// LDS: 2 buf x (A 256x64 + B 256x64) bf16 = 128 KiB -> 1 block/CU.
//
// Staging schedule per K-tile t (derived race-free for 2 buffers; every
// stage lands in a region whose readers finished >=1 phase earlier):
//   ph1: ds{B all, A mi=0}; stage A-q1q3(t+1) -> buf^1
//   ph2: ds{A mi=1};        stage B-h0(t+2)   -> buf   (B(t) done at ph1)
//   ph3: ds{A mi=2};        stage B-h1(t+2)   -> buf
//   ph4: ds{A mi=3};        stage A-q0q2(t+2) -> buf   (A q0q2(t) done ph2)
//        s_waitcnt vmcnt(6)  // 3 stages x 2 loads outstanding; certifies
//                            // all 8 loads of K-tile t+1. Never 0 mid-loop.
// Requires nt >= 3 (K = 1024 -> nt = 16 everywhere here).
// ---------------------------------------------------------------------------
struct G8Part {
    const ushort* A; const ushort* B; const float* bias;
    float* Cf; __hip_bfloat16* Cb;
    int act, lda, Nout, ldC;
};
struct G8Args { G8Part p[2]; int K, split; };

__device__ __forceinline__ void gemm8_body(
    const G8Part& P, int K, long m0, long n0, uint4* lds)
{
    const ushort* __restrict__ Ag = P.A;
    const ushort* __restrict__ Bg = P.B;
    const int lda = P.lda;

    const int tid  = threadIdx.x;
    const int wave = tid >> 6;
    const int lane = tid & 63;
    const int wr = wave >> 2, wcn = wave & 3;
    const int ln31 = lane & 31, blk = lane >> 5;
    const int sl = (wave << 6) + lane;          // 0..511 staging slot
    const int nt = K >> 6;

    uint4* Alds = lds;            // [2][2048] uint4
    uint4* Blds = lds + 4096;     // [2][2048]

#define STAGE_A(buf, qoff, kt)                                                 \
    {                                                                          \
        _Pragma("unroll")                                                      \
        for (int i_ = 0; i_ < 2; ++i_) {                                       \
            int r_  = (i_ << 7) + (qoff) + (sl >> 3);                          \
            int c_  = sl & 7;                                                  \
            int gk_ = (kt) + ((c_ ^ (r_ & 7)) << 3);                           \
            gld_lds16(Ag + (m0 + r_) * (long)lda + gk_,                        \
                      Alds + (buf) * 2048 + (((i_ << 7) + (qoff)) << 3) +      \
                          (wave << 6));                                        \
        }                                                                      \
    }
#define STAGE_B(buf, h, kt)                                                    \
    {                                                                          \
        _Pragma("unroll")                                                      \
        for (int i_ = 0; i_ < 2; ++i_) {                                       \
            int r_  = ((h) << 7) + (i_ << 6) + (sl >> 3);                      \
            int c_  = sl & 7;                                                  \
            int gk_ = (kt) + ((c_ ^ (r_ & 7)) << 3);                           \
            gld_lds16(Bg + (n0 + r_) * (long)K + gk_,                          \
                      Blds + (buf) * 2048 + ((((h) << 7) + (i_ << 6)) << 3) +  \
                          (wave << 6));                                        \
        }                                                                      \
    }
#define LDA_F(buf, mi)                                                         \
    _Pragma("unroll")                                                          \
    for (int ks_ = 0; ks_ < 4; ++ks_) {                                        \
        int r_ = wr * 128 + (mi) * 32 + ln31;                                  \
        int c_ = (ks_ * 2 + blk) ^ (r_ & 7);                                   \
        aF[ks_] = __builtin_bit_cast(bf16x8, Alds[(buf) * 2048 + r_ * 8 + c_]);\
    }
#define LDB_F(buf)                                                             \
    _Pragma("unroll")                                                          \
    for (int ni_ = 0; ni_ < 2; ++ni_) {                                        \
        _Pragma("unroll")                                                      \
        for (int ks_ = 0; ks_ < 4; ++ks_) {                                    \
            int r_ = wcn * 64 + ni_ * 32 + ln31;                               \
            int c_ = (ks_ * 2 + blk) ^ (r_ & 7);                               \
            bF[ni_][ks_] =                                                     \
                __builtin_bit_cast(bf16x8, Blds[(buf) * 2048 + r_ * 8 + c_]);  \
        }                                                                      \
    }
#define PHASE_MFMA(mi)                                                         \
    __builtin_amdgcn_s_barrier();                                              \
    asm volatile("s_waitcnt lgkmcnt(0)");                                      \
    __builtin_amdgcn_s_setprio(1);                                             \
    _Pragma("unroll")                                                          \
    for (int ks_ = 0; ks_ < 4; ++ks_) {                                        \
        _Pragma("unroll")                                                      \
        for (int ni_ = 0; ni_ < 2; ++ni_)                                      \
            acc[mi][ni_] = __builtin_amdgcn_mfma_f32_32x32x16_bf16(            \
                aF[ks_], bF[ni_][ks_], acc[mi][ni_], 0, 0, 0);                 \
    }                                                                          \
    __builtin_amdgcn_s_setprio(0);                                             \
    __builtin_amdgcn_s_barrier();

    // prologue: K-tile 0 fully + B(1) + A-q0q2(1)  (steady-state entry)
    STAGE_A(0, 0, 0);
    STAGE_A(0, 64, 0);
    STAGE_B(0, 0, 0);
    STAGE_B(0, 1, 0);
    STAGE_B(1, 0, 64);
    STAGE_B(1, 1, 64);
    STAGE_A(1, 0, 64);
    asm volatile("s_waitcnt vmcnt(6)");   // K-tile 0 certified
    __builtin_amdgcn_s_barrier();

    f32x16 acc[4][2];
#pragma unroll
    for (int i = 0; i < 4; ++i)
#pragma unroll
        for (int j = 0; j < 2; ++j) acc[i][j] = (f32x16)(0.0f);

    for (int t = 0; t < nt; ++t) {
        const int buf = t & 1;
        bf16x8 aF[4], bF[2][4];

        // ---- phase 1 ----
        LDB_F(buf);
        LDA_F(buf, 0);
        if (t + 1 < nt) STAGE_A(buf ^ 1, 64, (t + 1) << 6);
        PHASE_MFMA(0);

        // ---- phase 2 ----
        LDA_F(buf, 1);
        if (t + 2 < nt) STAGE_B(buf, 0, (t + 2) << 6);
        PHASE_MFMA(1);

        // ---- phase 3 ----
        LDA_F(buf, 2);
        if (t + 2 < nt) STAGE_B(buf, 1, (t + 2) << 6);
        PHASE_MFMA(2);

        // ---- phase 4 ----
        LDA_F(buf, 3);
        if (t + 2 < nt) STAGE_A(buf, 0, (t + 2) << 6);
        if (t < nt - 2) {
            asm volatile("s_waitcnt vmcnt(6)");   // counted, never 0
        } else if (t == nt - 2) {
            asm volatile("s_waitcnt vmcnt(0)");   // tail drain
        }
        PHASE_MFMA(3);
    }
#undef STAGE_A
#undef STAGE_B
#undef LDA_F
#undef LDB_F
#undef PHASE_MFMA

    // epilogue — proven 32x32 C/D mapping (row from reg, col from ln31)
    const int act = P.act, Nout = P.Nout, ldC = P.ldC;
    float bs2[2];
#pragma unroll
    for (int ni = 0; ni < 2; ++ni) {
        long col = n0 + wcn * 64 + ni * 32 + ln31;
        bs2[ni] = (col < Nout && P.bias) ? P.bias[col] : 0.0f;
    }
#pragma unroll
    for (int mi = 0; mi < 4; ++mi) {
#pragma unroll
        for (int ni = 0; ni < 2; ++ni) {
            long col = n0 + wcn * 64 + ni * 32 + ln31;
            if (col >= Nout) continue;
#pragma unroll
            for (int reg = 0; reg < 16; ++reg) {
                long row = m0 + wr * 128 + mi * 32 + (reg & 3) + 8 * (reg >> 2) + 4 * blk;
                float v = acc[mi][ni][reg] + bs2[ni];
                if (act == 1) {
                    v = fmaxf(v, 0.0f);
                    P.Cb[row * (long)ldC + col] = __float2bfloat16(v);
                } else if (act == 2) {
                    v = 1.0f / (1.0f + __expf(-v));
                    P.Cf[row * (long)ldC + col] = v;
                } else {
                    P.Cf[row * (long)ldC + col] = v;
                }
            }
        }
    }
}

__global__ __launch_bounds__(512, 2) void gemm8_k(G8Args g)
{
    __shared__ uint4 lds[8192];   // 128 KiB
    const int nwg = gridDim.x;    // always a multiple of 8 here
    const int cpx = nwg >> 3;
    const int bid = blockIdx.x;
    const int swz = (bid & 7) * cpx + (bid >> 3);   // bijective XCD swizzle

    long m0, n0;
    int part;
    if (swz < g.split) {
        part = 0;
        int ty = swz & 31;        // 32 row tiles (M = 8192), col-major decomp
        int tx = swz >> 5;        // consecutive swz share a B-panel per XCD
        m0 = (long)ty * 256;
        n0 = (long)tx * 256;
    } else {
        part = 1;                 // fused sel-L2 tile (Nout=64, B zero-padded)
        m0 = (long)(swz - g.split) * 256;
        n0 = 0;
    }
    gemm8_body(g.p[part], g.K, m0, n0, lds);
}

// ---------------------------------------------------------------------------
// Prep: batched transpose-cast (6 weights) + rmean + bias concat + x-cast
// ---------------------------------------------------------------------------
struct PrepArgs {
    const float* src[6];
    __hip_bfloat16* dst[6];
    int Nsrc[6];
    int Npad[6];
    const float* ranges; float* rmean;
    const float* b1; const float* b2; float* bcat;
    const float* x; __hip_bfloat16* xbf;
};

__global__ void prep_kernel(PrepArgs a)
{
    int z = blockIdx.z;
    int tx = threadIdx.x, ty = threadIdx.y;   // 32 x 8
    int t = ty * 32 + tx;
    if (z == 7) {
        int bid = blockIdx.y * 32 + blockIdx.x;   // 0..1023
        const float4* s4 = (const float4*)a.x;
        for (int i = bid * 256 + t; i < B_DIM * D_DIM / 4; i += 1024 * 256) {
            float4 v = s4[i];
            __hip_bfloat16* d = a.xbf + (size_t)i * 4;
            d[0] = __float2bfloat16(v.x);
            d[1] = __float2bfloat16(v.y);
            d[2] = __float2bfloat16(v.z);
            d[3] = __float2bfloat16(v.w);
        }
        return;
    }
    if (z == 6) {
        if (blockIdx.x || blockIdx.y) return;
        for (int j = t; j < NUM * C_DIM; j += 256) {
            float s = 0.0f;
#pragma unroll
            for (int k = 0; k < K_RANGES; ++k) s += a.ranges[j * K_RANGES + k];
            a.rmean[j] = s * (1.0f / K_RANGES);
        }
        for (int j = t; j < 1024; j += 256) {
            a.bcat[j]        = a.b1[j];
            a.bcat[1024 + j] = a.b2[j];
        }
        return;
    }
    const int Nsrc = a.Nsrc[z], Npad = a.Npad[z];
    int n0 = blockIdx.x * 32, k0 = blockIdx.y * 32;
    if (n0 >= Npad) return;
    const float* src = a.src[z];
    __hip_bfloat16* dst = a.dst[z];
    __shared__ float tile[32][33];
#pragma unroll
    for (int i = 0; i < 32; i += 8) {
        int k = k0 + ty + i, n = n0 + tx;
        tile[ty + i][tx] = (n < Nsrc) ? src[(size_t)k * Nsrc + n] : 0.0f;
    }
    __syncthreads();
#pragma unroll
    for (int i = 0; i < 32; i += 8) {
        int n = n0 + ty + i, k = k0 + tx;
        dst[(size_t)n * D_DIM + k] = __float2bfloat16(tile[tx][ty + i]);
    }
}

// ---------------------------------------------------------------------------
// Finalize: one thread per (b, n)
// ---------------------------------------------------------------------------
__global__ void finalize_kernel(
    const float* __restrict__ x, const float* __restrict__ truth,
    const float* __restrict__ ua, const float* __restrict__ ub,
    const float* __restrict__ gum, const float* __restrict__ rmean,
    const float* __restrict__ P, const float* __restrict__ W,
    float* __restrict__ out_truth, float* __restrict__ out_xcf)
{
    int idx = blockIdx.x * 256 + threadIdx.x;
    if (idx >= B_DIM * N_DIM) return;
    int b = idx >> 6, n = idx & 63;

    float tx = truth[idx];
    out_truth[idx] = tx;

    float p  = P[idx];
    float ea = -1.0f / logf(ua[idx]);
    float eb = -1.0f / logf(ub[idx]);
    float no = p * ea;
    float probs = no / (no + (1.0f - p) * eb);

    const float* Wrow = W + (size_t)idx * 16;
    const float* grow = gum + (size_t)idx * 16;
    float lo[16], g[16], xv[16];
#pragma unroll
    for (int c = 0; c < 16; c += 4) {
        float4 v = *(const float4*)(Wrow + c);
        lo[c] = v.x; lo[c + 1] = v.y; lo[c + 2] = v.z; lo[c + 3] = v.w;
        float4 gv = *(const float4*)(grow + c);
        g[c] = gv.x; g[c + 1] = gv.y; g[c + 2] = gv.z; g[c + 3] = gv.w;
    }

    bool needx = (n < NCAUSAL) || (n >= NUM);
    if (needx) {
        const float* xrow = x + (size_t)idx * 16;
#pragma unroll
        for (int c = 0; c < 16; c += 4) {
            float4 v = *(const float4*)(xrow + c);
            xv[c] = v.x; xv[c + 1] = v.y; xv[c + 2] = v.z; xv[c + 3] = v.w;
        }
    }

    if (n < NCAUSAL) {
        int curr = 0; float best = xv[0];
#pragma unroll
        for (int c = 1; c < 16; ++c)
            if (xv[c] > best) { best = xv[c]; curr = c; }
#pragma unroll
        for (int c = 0; c < 16; ++c) lo[c] += (c < curr) ? -100.0f : 1.0f;
    }

    float mx = lo[0];
#pragma unroll
    for (int c = 1; c < 16; ++c) mx = fmaxf(mx, lo[c]);
    float s = 0.0f, pr[16];
#pragma unroll
    for (int c = 0; c < 16; ++c) { pr[c] = __expf(lo[c] - mx); s += pr[c]; }
    float inv = 1.0f / s;
#pragma unroll
    for (int c = 0; c < 16; ++c)
        pr[c] = (1.0f - SMOOTH) * pr[c] * inv + (SMOOTH / C_DIM);

    float t[16];
    float mx2 = -1e30f;
#pragma unroll
    for (int c = 0; c < 16; ++c) {
        t[c] = (__logf(pr[c]) + g[c]) * (1.0f / TAU);
        mx2 = fmaxf(mx2, t[c]);
    }
    float s2 = 0.0f;
#pragma unroll
    for (int c = 0; c < 16; ++c) { t[c] = __expf(t[c] - mx2); s2 += t[c]; }
    float inv2 = 1.0f / s2;

    if (n < NUM) {
        float xt = 0.0f;
#pragma unroll
        for (int c = 0; c < 16; ++c) xt += t[c] * inv2 * rmean[n * 16 + c];
        out_xcf[(size_t)b * 544 + n] = probs * xt + (1.0f - probs) * tx;
    } else {
        float* o = out_xcf + (size_t)b * 544 + 32 + (size_t)(n - NUM) * 16;
#pragma unroll
        for (int c = 0; c < 16; ++c)
            o[c] = probs * t[c] * inv2 + (1.0f - probs) * xv[c];
    }
}

// ---------------------------------------------------------------------------
extern "C" void kernel_launch(void* const* d_in, const int* in_sizes, int n_in,
                              void* d_out, int out_size, void* d_ws, size_t ws_size,
                              hipStream_t stream)
{
    const float* x      = (const float*)d_in[0];
    const float* truth  = (const float*)d_in[1];
    const float* sel_w1 = (const float*)d_in[2];
    const float* sel_b1 = (const float*)d_in[3];
    const float* sel_w2 = (const float*)d_in[4];
    const float* sel_b2 = (const float*)d_in[5];
    const float* pw1    = (const float*)d_in[6];
    const float* pb1    = (const float*)d_in[7];
    const float* pw2    = (const float*)d_in[8];
    const float* pb2    = (const float*)d_in[9];
    const float* pw3    = (const float*)d_in[10];
    const float* pb3    = (const float*)d_in[11];
    const float* pw4    = (const float*)d_in[12];
    const float* pb4    = (const float*)d_in[13];
    const float* ranges = (const float*)d_in[14];
    const float* ua     = (const float*)d_in[15];
    const float* ub     = (const float*)d_in[16];
    const float* gum    = (const float*)d_in[17];

    float* out       = (float*)d_out;
    float* out_truth = out;                       // B*N
    float* out_xcf   = out + 524288;              // B*544
    float* out_P     = out + 4980736;             // B*N
    float* out_W     = out + 5505024;             // B*D

    // workspace layout (16B-aligned sections)
    char* w = (char*)d_ws;
    size_t off = 0;
    __hip_bfloat16* A0   = (__hip_bfloat16*)(w + off); off += (size_t)B_DIM * D_DIM * 2;
    __hip_bfloat16* act1 = (__hip_bfloat16*)(w + off); off += (size_t)B_DIM * 2048 * 2;
    __hip_bfloat16* actB = (__hip_bfloat16*)(w + off); off += (size_t)B_DIM * HP * 2;
    __hip_bfloat16* actC = (__hip_bfloat16*)(w + off); off += (size_t)B_DIM * HP * 2;
    __hip_bfloat16* Wcat = (__hip_bfloat16*)(w + off); off += (size_t)2048 * D_DIM * 2;
    __hip_bfloat16* w2t  = (__hip_bfloat16*)(w + off); off += (size_t)256 * HS * 2;   // padded to 256 rows
    __hip_bfloat16* p2t  = (__hip_bfloat16*)(w + off); off += (size_t)HP * HP * 2;
    __hip_bfloat16* p3t  = (__hip_bfloat16*)(w + off); off += (size_t)HP * HP * 2;
    __hip_bfloat16* p4t  = (__hip_bfloat16*)(w + off); off += (size_t)D_DIM * HP * 2;
    float* rmean         = (float*)(w + off);          off += 512 * 4;
    float* bcat          = (float*)(w + off);          off += 2048 * 4;
    if (ws_size < off) return;

    PrepArgs pa;
    pa.src[0] = sel_w1; pa.dst[0] = Wcat;               pa.Nsrc[0] = HS;    pa.Npad[0] = 1024;
    pa.src[1] = pw1;    pa.dst[1] = Wcat + 1024 * 1024; pa.Nsrc[1] = HP;    pa.Npad[1] = 1024;
    pa.src[2] = sel_w2; pa.dst[2] = w2t;                pa.Nsrc[2] = N_DIM; pa.Npad[2] = 256;
    pa.src[3] = pw2;    pa.dst[3] = p2t;                pa.Nsrc[3] = HP;    pa.Npad[3] = 1024;
    pa.src[4] = pw3;    pa.dst[4] = p3t;                pa.Nsrc[4] = HP;    pa.Npad[4] = 1024;
    pa.src[5] = pw4;    pa.dst[5] = p4t;                pa.Nsrc[5] = D_DIM; pa.Npad[5] = 1024;
    pa.ranges = ranges; pa.rmean = rmean;
    pa.b1 = sel_b1; pa.b2 = pb1; pa.bcat = bcat;
    pa.x = x; pa.xbf = A0;

    prep_kernel<<<dim3(32, 32, 8), dim3(32, 8), 0, stream>>>(pa);

    // L1 fused (sel + policy): A0 x Wcat^T -> act1 (B x 2048), relu
    {
        G8Args g{};
        g.p[0] = { (const ushort*)A0, (const ushort*)Wcat, bcat,
                   nullptr, act1, 1, 1024, 2048, 2048 };
        g.K = 1024; g.split = 256;
        gemm8_k<<<256, 512, 0, stream>>>(g);
    }
    // p2: act1[:,1024:] x p2t^T -> actB, relu
    {
        G8Args g{};
        g.p[0] = { (const ushort*)(act1 + 1024), (const ushort*)p2t, pb2,
                   nullptr, actB, 1, 2048, 1024, 1024 };
        g.K = 1024; g.split = 128;
        gemm8_k<<<128, 512, 0, stream>>>(g);
    }
    // p3 (+ fused sel-L2): blocks 0..127 -> p3 relu; 128..159 -> sel sigmoid
    {
        G8Args g{};
        g.p[0] = { (const ushort*)actB, (const ushort*)p3t, pb3,
                   nullptr, actC, 1, 1024, 1024, 1024 };
        g.p[1] = { (const ushort*)act1, (const ushort*)w2t, sel_b2,
                   out_P, nullptr, 2, 2048, 64, 64 };
        g.K = 1024; g.split = 128;
        gemm8_k<<<160, 512, 0, stream>>>(g);
    }
    // p4 -> W (f32, no act)
    {
        G8Args g{};
        g.p[0] = { (const ushort*)actC, (const ushort*)p4t, pb4,
                   out_W, nullptr, 0, 1024, 1024, 1024 };
        g.K = 1024; g.split = 128;
        gemm8_k<<<128, 512, 0, stream>>>(g);
    }

    finalize_kernel<<<(B_DIM * N_DIM + 255) / 256, 256, 0, stream>>>(
        x, truth, ua, ub, gum, rmean, out_P, out_W, out_truth, out_xcf);
}

// Round 3
// 306.274 us; speedup vs baseline: 1.1759x; 1.1759x over previous
//
#include <hip/hip_runtime.h>
#include <hip/hip_bf16.h>
#include <cstdint>

#define B_DIM 8192
#define N_DIM 64
#define C_DIM 16
#define D_DIM 1024
#define NUM 32
#define NCAUSAL 16
#define K_RANGES 8
#define HS 1024
#define HP 1024
#define TAU 0.7f
#define SMOOTH 0.1f

typedef __bf16 bf16x8 __attribute__((ext_vector_type(8)));
typedef float f32x16 __attribute__((ext_vector_type(16)));

typedef const __attribute__((address_space(1))) uint32_t* gas_ptr;
typedef __attribute__((address_space(3))) uint32_t* las_ptr;

__device__ __forceinline__ void gld_lds16(const void* g, void* l) {
    __builtin_amdgcn_global_load_lds((gas_ptr)(uintptr_t)g,
                                     (las_ptr)(uint32_t)(uintptr_t)l,
                                     16, 0, 0);
}

__device__ __forceinline__ int swz(int r) { return (r & 3) ^ ((r >> 2) & 3); }

// ---------------------------------------------------------------------------
// 8-wave 128x128 GEMM body. Same proven protocol as R0's gemm_body2
// (BK=32, dbuf LDS, one __syncthreads per K-step, swz chunk swizzle,
// identical accumulation order) but 512 threads = 8 waves (2Mx4N),
// per-wave 64x32, acc 2x f32x16 (~90 VGPR) -> 16+ waves/CU co-resident.
// Occupancy was the binding constraint (m132: 2 blk/CU = 508 TF,
// m97: 3 blk/CU = 874 TF); this doubles waves/CU at identical traffic.
// ACT: 0 = none (f32 out), 1 = relu (bf16 out), 2 = sigmoid (f32 out)
// ---------------------------------------------------------------------------
template <int ACT>
__device__ __forceinline__ void gemm_body8(
    const ushort* __restrict__ Ag, const ushort* __restrict__ Bg,
    const float* __restrict__ bias,
    float* __restrict__ Cf, __hip_bfloat16* __restrict__ Cb,
    int lda, int Nout, int ldC, int K, long m0, long n0,
    uint4 (*As)[512], uint4 (*Bs)[512])
{
    const int tid  = threadIdx.x;
    const int wave = tid >> 6;
    const int ln31 = tid & 31, blk = (tid >> 5) & 1;
    const int wr = wave >> 2, wc = wave & 3;

    // staging: 512 threads cover 512 slots (128 rows x 4 chunks) for A and B
    const int row = tid >> 2;
    const int ch  = (tid & 3) ^ swz(row);
    const ushort* aSrc = Ag + (m0 + row) * (long)lda + ch * 8;
    const ushort* bSrc = Bg + (n0 + row) * (long)K   + ch * 8;
    const int ldsOff = wave << 6;   // wave-uniform LDS base (lane offset implicit)

    f32x16 acc[2];
    acc[0] = (f32x16)(0.0f);
    acc[1] = (f32x16)(0.0f);

#define ISSUE_STAGE8(buf, kt)                                                  \
    {                                                                          \
        gld_lds16(aSrc + (kt), &As[buf][ldsOff]);                              \
        gld_lds16(bSrc + (kt), &Bs[buf][ldsOff]);                              \
    }

    ISSUE_STAGE8(0, 0);
    int cur = 0;
    for (int kt = 0; kt < K; kt += 32) {
        __syncthreads();   // drains vmcnt(0): buf 'cur' staged & all reads of buf cur^1 done
        if (kt + 32 < K) ISSUE_STAGE8(cur ^ 1, kt + 32);

        bf16x8 af[2][2], bfr[2];
#pragma unroll
        for (int ks = 0; ks < 2; ++ks) {
            int c = ks * 2 + blk;
#pragma unroll
            for (int mi = 0; mi < 2; ++mi) {
                int r = wr * 64 + mi * 32 + ln31;
                af[ks][mi] = __builtin_bit_cast(bf16x8, As[cur][r * 4 + (c ^ swz(r))]);
            }
            int n = wc * 32 + ln31;
            bfr[ks] = __builtin_bit_cast(bf16x8, Bs[cur][n * 4 + (c ^ swz(n))]);
        }
#pragma unroll
        for (int ks = 0; ks < 2; ++ks)
#pragma unroll
            for (int mi = 0; mi < 2; ++mi)
                acc[mi] = __builtin_amdgcn_mfma_f32_32x32x16_bf16(
                    af[ks][mi], bfr[ks], acc[mi], 0, 0, 0);
        cur ^= 1;
    }
#undef ISSUE_STAGE8

    // epilogue — proven 32x32 C/D mapping
    long col = n0 + wc * 32 + ln31;
    if (col < Nout) {
        float bs = bias ? bias[col] : 0.0f;
#pragma unroll
        for (int mi = 0; mi < 2; ++mi) {
#pragma unroll
            for (int reg = 0; reg < 16; ++reg) {
                long r2 = m0 + wr * 64 + mi * 32 + (reg & 3) + 8 * (reg >> 2) + 4 * blk;
                float v = acc[mi][reg] + bs;
                if (ACT == 1) {
                    v = fmaxf(v, 0.0f);
                    Cb[r2 * (long)ldC + col] = __float2bfloat16(v);
                } else if (ACT == 2) {
                    v = 1.0f / (1.0f + __expf(-v));
                    Cf[r2 * (long)ldC + col] = v;
                } else {
                    Cf[r2 * (long)ldC + col] = v;
                }
            }
        }
    }
}

template <int ACT>
__global__ __launch_bounds__(512, 4) void gemm8(
    const __hip_bfloat16* __restrict__ A, const __hip_bfloat16* __restrict__ Bt,
    const float* __restrict__ bias,
    float* __restrict__ Cf, __hip_bfloat16* __restrict__ Cb,
    int lda, int Nout, int ldC, int K)
{
    __shared__ uint4 As[2][512];
    __shared__ uint4 Bs[2][512];
    gemm_body8<ACT>((const ushort*)A, (const ushort*)Bt, bias, Cf, Cb,
                    lda, Nout, ldC, K,
                    (long)blockIdx.y * 128, (long)blockIdx.x * 128, As, Bs);
}

// Fused: blocks x<8 do p2 GEMM (relu bf16), block x==8 does sel-L2 (sigmoid f32).
__global__ __launch_bounds__(512, 4) void gemm8_fused23(
    const __hip_bfloat16* __restrict__ act1,   // B x 2048 (sel | policy)
    const __hip_bfloat16* __restrict__ p2t, const float* __restrict__ pb2,
    __hip_bfloat16* __restrict__ actB,
    const __hip_bfloat16* __restrict__ w2t, const float* __restrict__ sel_b2,
    float* __restrict__ outP)
{
    __shared__ uint4 As[2][512];
    __shared__ uint4 Bs[2][512];
    long m0 = (long)blockIdx.y * 128;
    if (blockIdx.x < 8) {
        gemm_body8<1>((const ushort*)(act1 + 1024), (const ushort*)p2t, pb2,
                      nullptr, actB, 2048, 1024, 1024, 1024,
                      m0, (long)blockIdx.x * 128, As, Bs);
    } else {
        gemm_body8<2>((const ushort*)act1, (const ushort*)w2t, sel_b2,
                      outP, nullptr, 2048, 64, 64, 1024,
                      m0, 0, As, Bs);
    }
}

// ---------------------------------------------------------------------------
// Prep: batched transpose-cast (6 weights) + rmean + bias concat + x-cast
// ---------------------------------------------------------------------------
struct PrepArgs {
    const float* src[6];
    __hip_bfloat16* dst[6];
    int Nsrc[6];
    int Npad[6];
    const float* ranges; float* rmean;
    const float* b1; const float* b2; float* bcat;
    const float* x; __hip_bfloat16* xbf;
};

__global__ void prep_kernel(PrepArgs a)
{
    int z = blockIdx.z;
    int tx = threadIdx.x, ty = threadIdx.y;   // 32 x 8
    int t = ty * 32 + tx;
    if (z == 7) {
        int bid = blockIdx.y * 32 + blockIdx.x;   // 0..1023
        const float4* s4 = (const float4*)a.x;
        for (int i = bid * 256 + t; i < B_DIM * D_DIM / 4; i += 1024 * 256) {
            float4 v = s4[i];
            __hip_bfloat16* d = a.xbf + (size_t)i * 4;
            d[0] = __float2bfloat16(v.x);
            d[1] = __float2bfloat16(v.y);
            d[2] = __float2bfloat16(v.z);
            d[3] = __float2bfloat16(v.w);
        }
        return;
    }
    if (z == 6) {
        if (blockIdx.x || blockIdx.y) return;
        for (int j = t; j < NUM * C_DIM; j += 256) {
            float s = 0.0f;
#pragma unroll
            for (int k = 0; k < K_RANGES; ++k) s += a.ranges[j * K_RANGES + k];
            a.rmean[j] = s * (1.0f / K_RANGES);
        }
        for (int j = t; j < 1024; j += 256) {
            a.bcat[j]        = a.b1[j];
            a.bcat[1024 + j] = a.b2[j];
        }
        return;
    }
    const int Nsrc = a.Nsrc[z], Npad = a.Npad[z];
    int n0 = blockIdx.x * 32, k0 = blockIdx.y * 32;
    if (n0 >= Npad) return;
    const float* src = a.src[z];
    __hip_bfloat16* dst = a.dst[z];
    __shared__ float tile[32][33];
#pragma unroll
    for (int i = 0; i < 32; i += 8) {
        int k = k0 + ty + i, n = n0 + tx;
        tile[ty + i][tx] = (n < Nsrc) ? src[(size_t)k * Nsrc + n] : 0.0f;
    }
    __syncthreads();
#pragma unroll
    for (int i = 0; i < 32; i += 8) {
        int n = n0 + ty + i, k = k0 + tx;
        dst[(size_t)n * D_DIM + k] = __float2bfloat16(tile[tx][ty + i]);
    }
}

// ---------------------------------------------------------------------------
// Finalize: one thread per (b, n)
// ---------------------------------------------------------------------------
__global__ void finalize_kernel(
    const float* __restrict__ x, const float* __restrict__ truth,
    const float* __restrict__ ua, const float* __restrict__ ub,
    const float* __restrict__ gum, const float* __restrict__ rmean,
    const float* __restrict__ P, const float* __restrict__ W,
    float* __restrict__ out_truth, float* __restrict__ out_xcf)
{
    int idx = blockIdx.x * 256 + threadIdx.x;
    if (idx >= B_DIM * N_DIM) return;
    int b = idx >> 6, n = idx & 63;

    float tx = truth[idx];
    out_truth[idx] = tx;

    float p  = P[idx];
    float ea = -1.0f / logf(ua[idx]);
    float eb = -1.0f / logf(ub[idx]);
    float no = p * ea;
    float probs = no / (no + (1.0f - p) * eb);

    const float* Wrow = W + (size_t)idx * 16;
    const float* grow = gum + (size_t)idx * 16;
    float lo[16], g[16], xv[16];
#pragma unroll
    for (int c = 0; c < 16; c += 4) {
        float4 v = *(const float4*)(Wrow + c);
        lo[c] = v.x; lo[c + 1] = v.y; lo[c + 2] = v.z; lo[c + 3] = v.w;
        float4 gv = *(const float4*)(grow + c);
        g[c] = gv.x; g[c + 1] = gv.y; g[c + 2] = gv.z; g[c + 3] = gv.w;
    }

    bool needx = (n < NCAUSAL) || (n >= NUM);
    if (needx) {
        const float* xrow = x + (size_t)idx * 16;
#pragma unroll
        for (int c = 0; c < 16; c += 4) {
            float4 v = *(const float4*)(xrow + c);
            xv[c] = v.x; xv[c + 1] = v.y; xv[c + 2] = v.z; xv[c + 3] = v.w;
        }
    }

    if (n < NCAUSAL) {
        int curr = 0; float best = xv[0];
#pragma unroll
        for (int c = 1; c < 16; ++c)
            if (xv[c] > best) { best = xv[c]; curr = c; }
#pragma unroll
        for (int c = 0; c < 16; ++c) lo[c] += (c < curr) ? -100.0f : 1.0f;
    }

    float mx = lo[0];
#pragma unroll
    for (int c = 1; c < 16; ++c) mx = fmaxf(mx, lo[c]);
    float s = 0.0f, pr[16];
#pragma unroll
    for (int c = 0; c < 16; ++c) { pr[c] = __expf(lo[c] - mx); s += pr[c]; }
    float inv = 1.0f / s;
#pragma unroll
    for (int c = 0; c < 16; ++c)
        pr[c] = (1.0f - SMOOTH) * pr[c] * inv + (SMOOTH / C_DIM);

    float t[16];
    float mx2 = -1e30f;
#pragma unroll
    for (int c = 0; c < 16; ++c) {
        t[c] = (__logf(pr[c]) + g[c]) * (1.0f / TAU);
        mx2 = fmaxf(mx2, t[c]);
    }
    float s2 = 0.0f;
#pragma unroll
    for (int c = 0; c < 16; ++c) { t[c] = __expf(t[c] - mx2); s2 += t[c]; }
    float inv2 = 1.0f / s2;

    if (n < NUM) {
        float xt = 0.0f;
#pragma unroll
        for (int c = 0; c < 16; ++c) xt += t[c] * inv2 * rmean[n * 16 + c];
        out_xcf[(size_t)b * 544 + n] = probs * xt + (1.0f - probs) * tx;
    } else {
        float* o = out_xcf + (size_t)b * 544 + 32 + (size_t)(n - NUM) * 16;
#pragma unroll
        for (int c = 0; c < 16; ++c)
            o[c] = probs * t[c] * inv2 + (1.0f - probs) * xv[c];
    }
}

// ---------------------------------------------------------------------------
extern "C" void kernel_launch(void* const* d_in, const int* in_sizes, int n_in,
                              void* d_out, int out_size, void* d_ws, size_t ws_size,
                              hipStream_t stream)
{
    const float* x      = (const float*)d_in[0];
    const float* truth  = (const float*)d_in[1];
    const float* sel_w1 = (const float*)d_in[2];
    const float* sel_b1 = (const float*)d_in[3];
    const float* sel_w2 = (const float*)d_in[4];
    const float* sel_b2 = (const float*)d_in[5];
    const float* pw1    = (const float*)d_in[6];
    const float* pb1    = (const float*)d_in[7];
    const float* pw2    = (const float*)d_in[8];
    const float* pb2    = (const float*)d_in[9];
    const float* pw3    = (const float*)d_in[10];
    const float* pb3    = (const float*)d_in[11];
    const float* pw4    = (const float*)d_in[12];
    const float* pb4    = (const float*)d_in[13];
    const float* ranges = (const float*)d_in[14];
    const float* ua     = (const float*)d_in[15];
    const float* ub     = (const float*)d_in[16];
    const float* gum    = (const float*)d_in[17];

    float* out       = (float*)d_out;
    float* out_truth = out;                       // B*N
    float* out_xcf   = out + 524288;              // B*544
    float* out_P     = out + 4980736;             // B*N
    float* out_W     = out + 5505024;             // B*D

    // workspace layout (16B-aligned sections)
    char* w = (char*)d_ws;
    size_t off = 0;
    __hip_bfloat16* A0   = (__hip_bfloat16*)(w + off); off += (size_t)B_DIM * D_DIM * 2;
    __hip_bfloat16* act1 = (__hip_bfloat16*)(w + off); off += (size_t)B_DIM * 2048 * 2;
    __hip_bfloat16* actB = (__hip_bfloat16*)(w + off); off += (size_t)B_DIM * HP * 2;
    __hip_bfloat16* actC = (__hip_bfloat16*)(w + off); off += (size_t)B_DIM * HP * 2;
    __hip_bfloat16* Wcat = (__hip_bfloat16*)(w + off); off += (size_t)2048 * D_DIM * 2;
    __hip_bfloat16* w2t  = (__hip_bfloat16*)(w + off); off += (size_t)128 * HS * 2;
    __hip_bfloat16* p2t  = (__hip_bfloat16*)(w + off); off += (size_t)HP * HP * 2;
    __hip_bfloat16* p3t  = (__hip_bfloat16*)(w + off); off += (size_t)HP * HP * 2;
    __hip_bfloat16* p4t  = (__hip_bfloat16*)(w + off); off += (size_t)D_DIM * HP * 2;
    float* rmean         = (float*)(w + off);          off += 512 * 4;
    float* bcat          = (float*)(w + off);          off += 2048 * 4;
    if (ws_size < off) return;

    PrepArgs pa;
    pa.src[0] = sel_w1; pa.dst[0] = Wcat;               pa.Nsrc[0] = HS;    pa.Npad[0] = 1024;
    pa.src[1] = pw1;    pa.dst[1] = Wcat + 1024 * 1024; pa.Nsrc[1] = HP;    pa.Npad[1] = 1024;
    pa.src[2] = sel_w2; pa.dst[2] = w2t;                pa.Nsrc[2] = N_DIM; pa.Npad[2] = 128;
    pa.src[3] = pw2;    pa.dst[3] = p2t;                pa.Nsrc[3] = HP;    pa.Npad[3] = 1024;
    pa.src[4] = pw3;    pa.dst[4] = p3t;                pa.Nsrc[4] = HP;    pa.Npad[4] = 1024;
    pa.src[5] = pw4;    pa.dst[5] = p4t;                pa.Nsrc[5] = D_DIM; pa.Npad[5] = 1024;
    pa.ranges = ranges; pa.rmean = rmean;
    pa.b1 = sel_b1; pa.b2 = pb1; pa.bcat = bcat;
    pa.x = x; pa.xbf = A0;

    prep_kernel<<<dim3(32, 32, 8), dim3(32, 8), 0, stream>>>(pa);

    // Layer 1 fused (sel + policy): A0 x Wcat^T -> act1 (B x 2048), relu
    // 128x128 tiles -> 1024 blocks -> 2-3 blocks/CU co-resident
    gemm8<1><<<dim3(16, 64), 512, 0, stream>>>(A0, Wcat, bcat, nullptr, act1,
                                               D_DIM, 2048, 2048, D_DIM);
    // p2 GEMM + sel layer-2 (fused launch) — 576 blocks
    gemm8_fused23<<<dim3(9, 64), 512, 0, stream>>>(act1, p2t, pb2, actB, w2t,
                                                   sel_b2, out_P);
    // p3 — 512 blocks
    gemm8<1><<<dim3(8, 64), 512, 0, stream>>>(actB, p3t, pb3, nullptr, actC,
                                              HP, HP, HP, HP);
    // p4 -> W — 512 blocks
    gemm8<0><<<dim3(8, 64), 512, 0, stream>>>(actC, p4t, pb4, out_W, nullptr,
                                              HP, D_DIM, D_DIM, HP);

    finalize_kernel<<<(B_DIM * N_DIM + 255) / 256, 256, 0, stream>>>(
        x, truth, ua, ub, gum, rmean, out_P, out_W, out_truth, out_xcf);
}

// Round 4
// 293.723 us; speedup vs baseline: 1.2261x; 1.0427x over previous
//
#include <hip/hip_runtime.h>
#include <hip/hip_bf16.h>
#include <cstdint>

#define B_DIM 8192
#define N_DIM 64
#define C_DIM 16
#define D_DIM 1024
#define NUM 32
#define NCAUSAL 16
#define K_RANGES 8
#define HS 1024
#define HP 1024
#define TAU 0.7f
#define SMOOTH 0.1f

typedef __bf16 bf16x8 __attribute__((ext_vector_type(8)));
typedef float f32x16 __attribute__((ext_vector_type(16)));

typedef const __attribute__((address_space(1))) uint32_t* gas_ptr;
typedef __attribute__((address_space(3))) uint32_t* las_ptr;

__device__ __forceinline__ void gld_lds16(const void* g, void* l) {
    __builtin_amdgcn_global_load_lds((gas_ptr)(uintptr_t)g,
                                     (las_ptr)(uint32_t)(uintptr_t)l,
                                     16, 0, 0);
}

__device__ __forceinline__ int swz(int r) { return (r & 3) ^ ((r >> 2) & 3); }

// ---------------------------------------------------------------------------
// 8-wave 128x128 GEMM body, counted-vmcnt 3-buffer pipeline (T4).
// R3-proven fragment/epilogue/accumulation structure (BK=32, swz chunk
// swizzle, 0 bank conflicts, absmax 0.015625) with the K-loop upgraded:
//   per K-step t: s_waitcnt vmcnt(2)  (certifies stage t; never 0 mid-loop)
//                 s_barrier            (one barrier per step, no vmem drain)
//                 issue stage t+2 -> buf[(t+2)%3]
//                 frag reads from buf[t%3] + 4 MFMA (unchanged order)
// Stage t+2 issued at iter t, certified at iter t+2 -> ~2 K-steps (~800cy)
// of HBM-latency cover vs ~400cy with the old __syncthreads vmcnt(0) drain.
// Race safety: write target buf[(t+2)%3] was last READ at iter t-1; those
// ds_reads are lgkm-retired before the iter-t barrier that precedes issue.
// ACT: 0 = none (f32 out), 1 = relu (bf16 out), 2 = sigmoid (f32 out)
// ---------------------------------------------------------------------------
template <int ACT>
__device__ __forceinline__ void gemm_body8(
    const ushort* __restrict__ Ag, const ushort* __restrict__ Bg,
    const float* __restrict__ bias,
    float* __restrict__ Cf, __hip_bfloat16* __restrict__ Cb,
    int lda, int Nout, int ldC, int K, long m0, long n0,
    uint4 (*As)[512], uint4 (*Bs)[512])
{
    const int tid  = threadIdx.x;
    const int wave = tid >> 6;
    const int ln31 = tid & 31, blk = (tid >> 5) & 1;
    const int wr = wave >> 2, wc = wave & 3;

    // staging: 512 threads cover 512 slots (128 rows x 4 chunks) for A and B
    const int row = tid >> 2;
    const int ch  = (tid & 3) ^ swz(row);
    const ushort* aSrc = Ag + (m0 + row) * (long)lda + ch * 8;
    const ushort* bSrc = Bg + (n0 + row) * (long)K   + ch * 8;
    const int ldsOff = wave << 6;   // wave-uniform LDS base (lane offset implicit)

    f32x16 acc[2];
    acc[0] = (f32x16)(0.0f);
    acc[1] = (f32x16)(0.0f);

#define ISSUE_STAGE8(buf, kt)                                                  \
    {                                                                          \
        gld_lds16(aSrc + (kt), &As[buf][ldsOff]);                              \
        gld_lds16(bSrc + (kt), &Bs[buf][ldsOff]);                              \
    }

    const int nt = K >> 5;
    // prologue: stage K-tiles 0 and 1 (4 vmem instrs outstanding)
    ISSUE_STAGE8(0, 0);
    ISSUE_STAGE8(1, 32);

    int rb = 0;   // read buffer = t % 3
    for (int t = 0; t < nt; ++t) {
        // certify stage t complete (oldest 2 of <=4 outstanding); tail drains
        if (t < nt - 1) {
            asm volatile("s_waitcnt vmcnt(2)" ::: "memory");
        } else {
            asm volatile("s_waitcnt vmcnt(0)" ::: "memory");
        }
        __builtin_amdgcn_s_barrier();

        // issue stage t+2 into buf[(t+2)%3] (its last readers ran at t-1,
        // ordered before this point by the barrier above)
        if (t + 2 < nt) {
            int sb = rb + 2; if (sb >= 3) sb -= 3;
            ISSUE_STAGE8(sb, (t + 2) * 32);
        }

        bf16x8 af[2][2], bfr[2];
#pragma unroll
        for (int ks = 0; ks < 2; ++ks) {
            int c = ks * 2 + blk;
#pragma unroll
            for (int mi = 0; mi < 2; ++mi) {
                int r = wr * 64 + mi * 32 + ln31;
                af[ks][mi] = __builtin_bit_cast(bf16x8, As[rb][r * 4 + (c ^ swz(r))]);
            }
            int n = wc * 32 + ln31;
            bfr[ks] = __builtin_bit_cast(bf16x8, Bs[rb][n * 4 + (c ^ swz(n))]);
        }
#pragma unroll
        for (int ks = 0; ks < 2; ++ks)
#pragma unroll
            for (int mi = 0; mi < 2; ++mi)
                acc[mi] = __builtin_amdgcn_mfma_f32_32x32x16_bf16(
                    af[ks][mi], bfr[ks], acc[mi], 0, 0, 0);

        rb = (rb == 2) ? 0 : rb + 1;
    }
#undef ISSUE_STAGE8

    // epilogue — proven 32x32 C/D mapping
    long col = n0 + wc * 32 + ln31;
    if (col < Nout) {
        float bs = bias ? bias[col] : 0.0f;
#pragma unroll
        for (int mi = 0; mi < 2; ++mi) {
#pragma unroll
            for (int reg = 0; reg < 16; ++reg) {
                long r2 = m0 + wr * 64 + mi * 32 + (reg & 3) + 8 * (reg >> 2) + 4 * blk;
                float v = acc[mi][reg] + bs;
                if (ACT == 1) {
                    v = fmaxf(v, 0.0f);
                    Cb[r2 * (long)ldC + col] = __float2bfloat16(v);
                } else if (ACT == 2) {
                    v = 1.0f / (1.0f + __expf(-v));
                    Cf[r2 * (long)ldC + col] = v;
                } else {
                    Cf[r2 * (long)ldC + col] = v;
                }
            }
        }
    }
}

// bijective XCD swizzle (all grids here have nwg % 8 == 0): HW dispatch
// round-robins blocks across 8 XCDs; remap so each XCD gets a contiguous
// strip of tiles -> A/B panels become L2-resident per XCD (T1).
__device__ __forceinline__ void xcd_remap(int& bx, int& by)
{
    int gx  = gridDim.x;
    int nwg = gx * gridDim.y;
    int lin = by * gx + bx;
    int cpx = nwg >> 3;
    int sw  = (lin & 7) * cpx + (lin >> 3);
    by = sw / gx;
    bx = sw - by * gx;
}

template <int ACT>
__global__ __launch_bounds__(512, 4) void gemm8(
    const __hip_bfloat16* __restrict__ A, const __hip_bfloat16* __restrict__ Bt,
    const float* __restrict__ bias,
    float* __restrict__ Cf, __hip_bfloat16* __restrict__ Cb,
    int lda, int Nout, int ldC, int K)
{
    __shared__ uint4 As[3][512];
    __shared__ uint4 Bs[3][512];
    int bx = blockIdx.x, by = blockIdx.y;
    xcd_remap(bx, by);
    gemm_body8<ACT>((const ushort*)A, (const ushort*)Bt, bias, Cf, Cb,
                    lda, Nout, ldC, K,
                    (long)by * 128, (long)bx * 128, As, Bs);
}

// Fused: blocks x<8 do p2 GEMM (relu bf16), block x==8 does sel-L2 (sigmoid f32).
__global__ __launch_bounds__(512, 4) void gemm8_fused23(
    const __hip_bfloat16* __restrict__ act1,   // B x 2048 (sel | policy)
    const __hip_bfloat16* __restrict__ p2t, const float* __restrict__ pb2,
    __hip_bfloat16* __restrict__ actB,
    const __hip_bfloat16* __restrict__ w2t, const float* __restrict__ sel_b2,
    float* __restrict__ outP)
{
    __shared__ uint4 As[3][512];
    __shared__ uint4 Bs[3][512];
    int bx = blockIdx.x, by = blockIdx.y;
    xcd_remap(bx, by);
    long m0 = (long)by * 128;
    if (bx < 8) {
        gemm_body8<1>((const ushort*)(act1 + 1024), (const ushort*)p2t, pb2,
                      nullptr, actB, 2048, 1024, 1024, 1024,
                      m0, (long)bx * 128, As, Bs);
    } else {
        gemm_body8<2>((const ushort*)act1, (const ushort*)w2t, sel_b2,
                      outP, nullptr, 2048, 64, 64, 1024,
                      m0, 0, As, Bs);
    }
}

// ---------------------------------------------------------------------------
// Prep: batched transpose-cast (6 weights) + rmean + bias concat + x-cast
// ---------------------------------------------------------------------------
struct PrepArgs {
    const float* src[6];
    __hip_bfloat16* dst[6];
    int Nsrc[6];
    int Npad[6];
    const float* ranges; float* rmean;
    const float* b1; const float* b2; float* bcat;
    const float* x; __hip_bfloat16* xbf;
};

__global__ void prep_kernel(PrepArgs a)
{
    int z = blockIdx.z;
    int tx = threadIdx.x, ty = threadIdx.y;   // 32 x 8
    int t = ty * 32 + tx;
    if (z == 7) {
        int bid = blockIdx.y * 32 + blockIdx.x;   // 0..1023
        const float4* s4 = (const float4*)a.x;
        for (int i = bid * 256 + t; i < B_DIM * D_DIM / 4; i += 1024 * 256) {
            float4 v = s4[i];
            __hip_bfloat16* d = a.xbf + (size_t)i * 4;
            d[0] = __float2bfloat16(v.x);
            d[1] = __float2bfloat16(v.y);
            d[2] = __float2bfloat16(v.z);
            d[3] = __float2bfloat16(v.w);
        }
        return;
    }
    if (z == 6) {
        if (blockIdx.x || blockIdx.y) return;
        for (int j = t; j < NUM * C_DIM; j += 256) {
            float s = 0.0f;
#pragma unroll
            for (int k = 0; k < K_RANGES; ++k) s += a.ranges[j * K_RANGES + k];
            a.rmean[j] = s * (1.0f / K_RANGES);
        }
        for (int j = t; j < 1024; j += 256) {
            a.bcat[j]        = a.b1[j];
            a.bcat[1024 + j] = a.b2[j];
        }
        return;
    }
    const int Nsrc = a.Nsrc[z], Npad = a.Npad[z];
    int n0 = blockIdx.x * 32, k0 = blockIdx.y * 32;
    if (n0 >= Npad) return;
    const float* src = a.src[z];
    __hip_bfloat16* dst = a.dst[z];
    __shared__ float tile[32][33];
#pragma unroll
    for (int i = 0; i < 32; i += 8) {
        int k = k0 + ty + i, n = n0 + tx;
        tile[ty + i][tx] = (n < Nsrc) ? src[(size_t)k * Nsrc + n] : 0.0f;
    }
    __syncthreads();
#pragma unroll
    for (int i = 0; i < 32; i += 8) {
        int n = n0 + ty + i, k = k0 + tx;
        dst[(size_t)n * D_DIM + k] = __float2bfloat16(tile[tx][ty + i]);
    }
}

// ---------------------------------------------------------------------------
// Finalize: one thread per (b, n)
// ---------------------------------------------------------------------------
__global__ void finalize_kernel(
    const float* __restrict__ x, const float* __restrict__ truth,
    const float* __restrict__ ua, const float* __restrict__ ub,
    const float* __restrict__ gum, const float* __restrict__ rmean,
    const float* __restrict__ P, const float* __restrict__ W,
    float* __restrict__ out_truth, float* __restrict__ out_xcf)
{
    int idx = blockIdx.x * 256 + threadIdx.x;
    if (idx >= B_DIM * N_DIM) return;
    int b = idx >> 6, n = idx & 63;

    float tx = truth[idx];
    out_truth[idx] = tx;

    float p  = P[idx];
    float ea = -1.0f / logf(ua[idx]);
    float eb = -1.0f / logf(ub[idx]);
    float no = p * ea;
    float probs = no / (no + (1.0f - p) * eb);

    const float* Wrow = W + (size_t)idx * 16;
    const float* grow = gum + (size_t)idx * 16;
    float lo[16], g[16], xv[16];
#pragma unroll
    for (int c = 0; c < 16; c += 4) {
        float4 v = *(const float4*)(Wrow + c);
        lo[c] = v.x; lo[c + 1] = v.y; lo[c + 2] = v.z; lo[c + 3] = v.w;
        float4 gv = *(const float4*)(grow + c);
        g[c] = gv.x; g[c + 1] = gv.y; g[c + 2] = gv.z; g[c + 3] = gv.w;
    }

    bool needx = (n < NCAUSAL) || (n >= NUM);
    if (needx) {
        const float* xrow = x + (size_t)idx * 16;
#pragma unroll
        for (int c = 0; c < 16; c += 4) {
            float4 v = *(const float4*)(xrow + c);
            xv[c] = v.x; xv[c + 1] = v.y; xv[c + 2] = v.z; xv[c + 3] = v.w;
        }
    }

    if (n < NCAUSAL) {
        int curr = 0; float best = xv[0];
#pragma unroll
        for (int c = 1; c < 16; ++c)
            if (xv[c] > best) { best = xv[c]; curr = c; }
#pragma unroll
        for (int c = 0; c < 16; ++c) lo[c] += (c < curr) ? -100.0f : 1.0f;
    }

    float mx = lo[0];
#pragma unroll
    for (int c = 1; c < 16; ++c) mx = fmaxf(mx, lo[c]);
    float s = 0.0f, pr[16];
#pragma unroll
    for (int c = 0; c < 16; ++c) { pr[c] = __expf(lo[c] - mx); s += pr[c]; }
    float inv = 1.0f / s;
#pragma unroll
    for (int c = 0; c < 16; ++c)
        pr[c] = (1.0f - SMOOTH) * pr[c] * inv + (SMOOTH / C_DIM);

    float t[16];
    float mx2 = -1e30f;
#pragma unroll
    for (int c = 0; c < 16; ++c) {
        t[c] = (__logf(pr[c]) + g[c]) * (1.0f / TAU);
        mx2 = fmaxf(mx2, t[c]);
    }
    float s2 = 0.0f;
#pragma unroll
    for (int c = 0; c < 16; ++c) { t[c] = __expf(t[c] - mx2); s2 += t[c]; }
    float inv2 = 1.0f / s2;

    if (n < NUM) {
        float xt = 0.0f;
#pragma unroll
        for (int c = 0; c < 16; ++c) xt += t[c] * inv2 * rmean[n * 16 + c];
        out_xcf[(size_t)b * 544 + n] = probs * xt + (1.0f - probs) * tx;
    } else {
        float* o = out_xcf + (size_t)b * 544 + 32 + (size_t)(n - NUM) * 16;
#pragma unroll
        for (int c = 0; c < 16; ++c)
            o[c] = probs * t[c] * inv2 + (1.0f - probs) * xv[c];
    }
}

// ---------------------------------------------------------------------------
extern "C" void kernel_launch(void* const* d_in, const int* in_sizes, int n_in,
                              void* d_out, int out_size, void* d_ws, size_t ws_size,
                              hipStream_t stream)
{
    const float* x      = (const float*)d_in[0];
    const float* truth  = (const float*)d_in[1];
    const float* sel_w1 = (const float*)d_in[2];
    const float* sel_b1 = (const float*)d_in[3];
    const float* sel_w2 = (const float*)d_in[4];
    const float* sel_b2 = (const float*)d_in[5];
    const float* pw1    = (const float*)d_in[6];
    const float* pb1    = (const float*)d_in[7];
    const float* pw2    = (const float*)d_in[8];
    const float* pb2    = (const float*)d_in[9];
    const float* pw3    = (const float*)d_in[10];
    const float* pb3    = (const float*)d_in[11];
    const float* pw4    = (const float*)d_in[12];
    const float* pb4    = (const float*)d_in[13];
    const float* ranges = (const float*)d_in[14];
    const float* ua     = (const float*)d_in[15];
    const float* ub     = (const float*)d_in[16];
    const float* gum    = (const float*)d_in[17];

    float* out       = (float*)d_out;
    float* out_truth = out;                       // B*N
    float* out_xcf   = out + 524288;              // B*544
    float* out_P     = out + 4980736;             // B*N
    float* out_W     = out + 5505024;             // B*D

    // workspace layout (16B-aligned sections)
    char* w = (char*)d_ws;
    size_t off = 0;
    __hip_bfloat16* A0   = (__hip_bfloat16*)(w + off); off += (size_t)B_DIM * D_DIM * 2;
    __hip_bfloat16* act1 = (__hip_bfloat16*)(w + off); off += (size_t)B_DIM * 2048 * 2;
    __hip_bfloat16* actB = (__hip_bfloat16*)(w + off); off += (size_t)B_DIM * HP * 2;
    __hip_bfloat16* actC = (__hip_bfloat16*)(w + off); off += (size_t)B_DIM * HP * 2;
    __hip_bfloat16* Wcat = (__hip_bfloat16*)(w + off); off += (size_t)2048 * D_DIM * 2;
    __hip_bfloat16* w2t  = (__hip_bfloat16*)(w + off); off += (size_t)128 * HS * 2;
    __hip_bfloat16* p2t  = (__hip_bfloat16*)(w + off); off += (size_t)HP * HP * 2;
    __hip_bfloat16* p3t  = (__hip_bfloat16*)(w + off); off += (size_t)HP * HP * 2;
    __hip_bfloat16* p4t  = (__hip_bfloat16*)(w + off); off += (size_t)D_DIM * HP * 2;
    float* rmean         = (float*)(w + off);          off += 512 * 4;
    float* bcat          = (float*)(w + off);          off += 2048 * 4;
    if (ws_size < off) return;

    PrepArgs pa;
    pa.src[0] = sel_w1; pa.dst[0] = Wcat;               pa.Nsrc[0] = HS;    pa.Npad[0] = 1024;
    pa.src[1] = pw1;    pa.dst[1] = Wcat + 1024 * 1024; pa.Nsrc[1] = HP;    pa.Npad[1] = 1024;
    pa.src[2] = sel_w2; pa.dst[2] = w2t;                pa.Nsrc[2] = N_DIM; pa.Npad[2] = 128;
    pa.src[3] = pw2;    pa.dst[3] = p2t;                pa.Nsrc[3] = HP;    pa.Npad[3] = 1024;
    pa.src[4] = pw3;    pa.dst[4] = p3t;                pa.Nsrc[4] = HP;    pa.Npad[4] = 1024;
    pa.src[5] = pw4;    pa.dst[5] = p4t;                pa.Nsrc[5] = D_DIM; pa.Npad[5] = 1024;
    pa.ranges = ranges; pa.rmean = rmean;
    pa.b1 = sel_b1; pa.b2 = pb1; pa.bcat = bcat;
    pa.x = x; pa.xbf = A0;

    prep_kernel<<<dim3(32, 32, 8), dim3(32, 8), 0, stream>>>(pa);

    // Layer 1 fused (sel + policy): A0 x Wcat^T -> act1 (B x 2048), relu
    gemm8<1><<<dim3(16, 64), 512, 0, stream>>>(A0, Wcat, bcat, nullptr, act1,
                                               D_DIM, 2048, 2048, D_DIM);
    // p2 GEMM + sel layer-2 (fused launch) — 576 blocks
    gemm8_fused23<<<dim3(9, 64), 512, 0, stream>>>(act1, p2t, pb2, actB, w2t,
                                                   sel_b2, out_P);
    // p3 — 512 blocks
    gemm8<1><<<dim3(8, 64), 512, 0, stream>>>(actB, p3t, pb3, nullptr, actC,
                                              HP, HP, HP, HP);
    // p4 -> W — 512 blocks
    gemm8<0><<<dim3(8, 64), 512, 0, stream>>>(actC, p4t, pb4, out_W, nullptr,
                                              HP, D_DIM, D_DIM, HP);

    finalize_kernel<<<(B_DIM * N_DIM + 255) / 256, 256, 0, stream>>>(
        x, truth, ua, ub, gum, rmean, out_P, out_W, out_truth, out_xcf);
}